// Round 10
// baseline (82.018 us; speedup 1.0000x reference)
//
#include <hip/hip_runtime.h>
#include <hip/hip_bf16.h>
#include <math.h>

#define BATCH 4
#define SEQ   2048
#define DIM   1024
#define HEAD  64
#define NCHUNK ((BATCH * SEQ * SEQ) / 64)   // 262144 64-bool chunks

typedef __attribute__((ext_vector_type(8))) short bf16x8;
typedef __attribute__((ext_vector_type(4))) short bf16x4;
typedef __attribute__((ext_vector_type(4))) float f32x4;

static __device__ __forceinline__ short f2bf(float f) {
    __hip_bfloat16 h = __float2bfloat16(f);     // RNE
    return *reinterpret_cast<short*>(&h);
}

// ---------------------------------------------------------------------------
// Prelude: W[1024][64] f32 -> frag-major Wt2[which][k/32][64][32] bf16, so a
// proj wave's B-frag load (n,c,g lanes) is one contiguous 1KB segment.
// Plus mask dtype detect (int32 bools are {0,1}; byte-bools read as u32
// exceed 1 w.p. 7/8 per word).
// ---------------------------------------------------------------------------
__global__ __launch_bounds__(256) void wconv_detect_kernel(
    const float* __restrict__ Wq, const float* __restrict__ Wk, const float* __restrict__ Wv,
    short* __restrict__ Wt, const unsigned int* __restrict__ mask_u32,
    int* __restrict__ mflag)
{
    const int which = blockIdx.y;
    const float* __restrict__ W = (which == 0) ? Wq : (which == 1) ? Wk : Wv;
    short* __restrict__ Wtw = Wt + (size_t)which * HEAD * DIM;

    const int h  = threadIdx.x & 63;
    const int k0 = blockIdx.x * 64 + (threadIdx.x >> 6) * 16;
    #pragma unroll
    for (int j = 0; j < 16; ++j) {
        int k = k0 + j;
        Wtw[((size_t)(k >> 5) * 64 + h) * 32 + (k & 31)] =
            f2bf(W[(size_t)k * HEAD + h]);
    }

    if (blockIdx.x == 0 && blockIdx.y == 0 && threadIdx.x < 64) {
        int lane = threadIdx.x;
        bool weird = false;
        for (int i = lane; i < 1024; i += 64) weird |= (mask_u32[i] > 1u);
        unsigned long long b = __ballot(weird);
        if (lane == 0) *mflag = (b != 0ull) ? 1 : 0;
    }
}

// ---------------------------------------------------------------------------
// Projection v7: X[8192,1024]f32 @ W -> bf16 Q/K/Vt.
// 1536 blocks x 256 threads: 16 rows x 64 cols per block, 4 waves split-K
// (256 each), f32 partials merged through 16 KB LDS.
// KEY FIX vs R7/R8: sched_barrier(0) after each half's load cluster pins all
// 24 loads (8 X dwordx4 + 16 W dwordx4) ABOVE the compute, forcing ~96 load
// results live across the fence -> allocator must keep them in registers and
// the loads stay in flight together (pack_kernel-style MLP, 6.1 TB/s proof).
// __launch_bounds__(256,2) raises the VGPR cap to 256 so it can.
// Half-1 loads share a scheduling region with half-0 compute (free overlap).
// ---------------------------------------------------------------------------
__global__ __launch_bounds__(256, 2) void proj7_kernel(
    const float* __restrict__ Xq, const float* __restrict__ Xk, const float* __restrict__ Xv,
    const short* __restrict__ Wt,
    short* __restrict__ Q, short* __restrict__ K, short* __restrict__ Vt)
{
    const int which = blockIdx.x >> 9;          // 0:Q 1:K 2:V
    const int row0  = (blockIdx.x & 511) * 16;  // global row (b*S+s)
    const float* __restrict__ X = (which == 0) ? Xq : (which == 1) ? Xk : Xv;
    const short* __restrict__ Wtw = Wt + (size_t)which * HEAD * DIM;

    const int tid  = threadIdx.x;
    const int lane = tid & 63;
    const int w    = tid >> 6;                  // wave = K-chunk of 256
    const int g    = lane >> 4;
    const int c    = lane & 15;

    __shared__ float O_lds[4][16][64];          // [wave][row][col] partials

    const float* __restrict__ Xp = X + (size_t)(row0 + c) * DIM + w * 256 + g * 8;
    // frag-major W: chunk (w*8 + half*4 + s), lane offset (n*16+c)*32 + g*8
    const short* __restrict__ Wp = Wtw + (size_t)(w * 8) * 2048 + c * 32 + g * 8;

    f32x4 acc[4];
    #pragma unroll
    for (int n = 0; n < 4; ++n) acc[n] = (f32x4)0.0f;

    #pragma unroll
    for (int half = 0; half < 2; ++half) {
        // --- all X loads for this half (8 independent 16B) ---
        f32x4 xa[4], xb[4];
        #pragma unroll
        for (int s = 0; s < 4; ++s) {
            xa[s] = *(const f32x4*)(Xp + half * 128 + s * 32);
            xb[s] = *(const f32x4*)(Xp + half * 128 + s * 32 + 4);
        }
        // --- all W frag loads for this half (16 independent 16B, 1KB/wave) ---
        bf16x8 wf[16];
        #pragma unroll
        for (int s = 0; s < 4; ++s)
            #pragma unroll
            for (int n = 0; n < 4; ++n)
                wf[s * 4 + n] = *(const bf16x8*)(Wp + (size_t)(half * 4 + s) * 2048
                                                 + n * 512);
        // Pin the 24 loads above the compute: nothing crosses this fence.
        __builtin_amdgcn_sched_barrier(0);
        // --- compute ---
        #pragma unroll
        for (int s = 0; s < 4; ++s) {
            bf16x8 a;
            a[0]=f2bf(xa[s][0]); a[1]=f2bf(xa[s][1]); a[2]=f2bf(xa[s][2]); a[3]=f2bf(xa[s][3]);
            a[4]=f2bf(xb[s][0]); a[5]=f2bf(xb[s][1]); a[6]=f2bf(xb[s][2]); a[7]=f2bf(xb[s][3]);
            #pragma unroll
            for (int n = 0; n < 4; ++n)
                acc[n] = __builtin_amdgcn_mfma_f32_16x16x32_bf16(a, wf[s * 4 + n],
                                                                 acc[n], 0, 0, 0);
        }
    }

    // publish partials: C/D layout col = lane&15 (W col), row = g*4+reg (X row)
    #pragma unroll
    for (int n = 0; n < 4; ++n)
        #pragma unroll
        for (int r = 0; r < 4; ++r)
            O_lds[w][g * 4 + r][n * 16 + c] = acc[n][r];
    __syncthreads();

    if (which < 2) {
        short* dst = (which == 0) ? Q : K;
        const int trow = tid >> 4, c4 = (tid & 15) * 4;
        f32x4 sum = *(const f32x4*)&O_lds[0][trow][c4];
        #pragma unroll
        for (int i = 1; i < 4; ++i) {
            f32x4 t = *(const f32x4*)&O_lds[i][trow][c4];
            sum[0] += t[0]; sum[1] += t[1]; sum[2] += t[2]; sum[3] += t[3];
        }
        bf16x4 pk;
        #pragma unroll
        for (int j = 0; j < 4; ++j) pk[j] = f2bf(sum[j]);
        *(bf16x4*)&dst[(size_t)(row0 + trow) * HEAD + c4] = pk;
    } else {
        // Vt[b][h][s]: thread owns one h, 4 consecutive s
        const int h = tid & 63, r4 = (tid >> 6) * 4;
        const int b = row0 >> 11, sb = row0 & (SEQ - 1);
        bf16x4 pk;
        #pragma unroll
        for (int j = 0; j < 4; ++j) {
            float v = O_lds[0][r4 + j][h] + O_lds[1][r4 + j][h]
                    + O_lds[2][r4 + j][h] + O_lds[3][r4 + j][h];
            pk[j] = f2bf(v);
        }
        *(bf16x4*)&Vt[((size_t)(b * HEAD + h)) * SEQ + sb + r4] = pk;
    }
}

// ---------------------------------------------------------------------------
// Mask bit-pack: 16 independent 256B loads in flight per wave,
// 512 blocks x 4 waves; wave owns 128 consecutive chunks. (6.1 TB/s, at floor)
// ---------------------------------------------------------------------------
__global__ __launch_bounds__(256) void pack_kernel(
    const void* __restrict__ mask, const int* __restrict__ mflag,
    unsigned long long* __restrict__ packed)
{
    const int lane = threadIdx.x & 63;
    const int gw   = blockIdx.x * 4 + (threadIdx.x >> 6);   // 0..2047
    const int c0   = gw * 128;
    const int useByte = *mflag;
    if (useByte) {
        const unsigned char* mb = (const unsigned char*)mask;
        for (int i = 0; i < 8; ++i) {
            unsigned char v[16];
            #pragma unroll
            for (int j = 0; j < 16; ++j)
                v[j] = mb[(size_t)(c0 + i * 16 + j) * 64 + lane];
            #pragma unroll
            for (int j = 0; j < 16; ++j) {
                unsigned long long bb = __ballot(v[j] != 0);
                if (lane == 0) packed[c0 + i * 16 + j] = bb;
            }
        }
    } else {
        const unsigned int* mw = (const unsigned int*)mask;
        for (int i = 0; i < 8; ++i) {
            unsigned int v[16];
            #pragma unroll
            for (int j = 0; j < 16; ++j)
                v[j] = mw[(size_t)(c0 + i * 16 + j) * 64 + lane];
            #pragma unroll
            for (int j = 0; j < 16; ++j) {
                unsigned long long bb = __ballot(v[j] != 0);
                if (lane == 0) packed[c0 + i * 16 + j] = bb;
            }
        }
    }
}

// ---------------------------------------------------------------------------
// Flash attention: grid (S/16, B), 512 threads = 8 waves; wave w owns keys
// [w*256,(w+1)*256). Swapped QK^T (S^T = mfma(K,Q)) puts a full q-row in-lane:
// softmax reduce = in-lane tree + 2 shfl_xor. Mask preloaded as 8 bit-words
// per lane. Defer-max rescale (THR=8). P->LDS transpose -> PV MFMA.
// ---------------------------------------------------------------------------
__global__ __launch_bounds__(512, 4) void attn_kernel(
    const short* __restrict__ Q, const short* __restrict__ K, const short* __restrict__ Vt,
    const unsigned int* __restrict__ packed, float* __restrict__ out)
{
    const int qbase = blockIdx.x * 16;
    const int b     = blockIdx.y;
    const int tid  = threadIdx.x;
    const int lane = tid & 63;
    const int w    = tid >> 6;          // wave 0..7 = key segment
    const int g    = lane >> 4;
    const int c    = lane & 15;

    const short* Qb = Q  + (size_t)(b * SEQ + qbase) * HEAD;
    const short* Kb = K  + (size_t)b * SEQ * HEAD;
    const short* Vb = Vt + (size_t)b * HEAD * SEQ;

    // LDS: P (loop phase, 8KB) aliases O (merge phase, 32KB); M/L after.
    __shared__ __align__(16) unsigned char smem[32768 + 1024];
    short (*P_lds)[4][16][8] = (short (*)[4][16][8])smem;   // [wave][kgrp][q][8]
    float (*O_lds)[16][64]   = (float (*)[16][64])smem;     // [wave][q][h]
    float (*M_lds)[16] = (float (*)[16])(smem + 32768);     // [wave][q]
    float (*L_lds)[16] = (float (*)[16])(smem + 32768 + 512);

    // per-lane mask bits for q = qbase+c, keys w*256..w*256+255 (8 u32 words)
    const unsigned int* pw = packed + (size_t)(b * SEQ + qbase + c) * 64 + w * 8;
    unsigned int mwords[8];
    #pragma unroll
    for (int i = 0; i < 8; ++i) mwords[i] = pw[i];

    // Q as B-operand fragments (col q = c, k = head dim)
    bf16x8 qb0 = *(const bf16x8*)&Qb[c * HEAD + g * 8];
    bf16x8 qb1 = *(const bf16x8*)&Qb[c * HEAD + 32 + g * 8];

    float m_run = -INFINITY, l_run = 0.0f;
    f32x4 o[4];
    #pragma unroll
    for (int n = 0; n < 4; ++n) o[n] = (f32x4)0.0f;

    const float scale = 0.125f;                    // HEAD^-0.5
    const float LOG2E = 1.44269504088896340736f;

    for (int i = 0; i < 8; ++i) {
        const int kt = w * 8 + i;                  // key tile of 32
        const short* Kt = Kb + (size_t)kt * 32 * HEAD;

        // V^T B-fragments (issued early, independent of QK chain)
        bf16x8 vb[4];
        #pragma unroll
        for (int n = 0; n < 4; ++n)
            vb[n] = *(const bf16x8*)&Vb[(size_t)(n * 16 + c) * SEQ + kt * 32 + g * 8];

        // K as A-operand (row = key = c / 16+c, k = head dim)
        bf16x8 ka00 = *(const bf16x8*)&Kt[c * HEAD + g * 8];
        bf16x8 ka01 = *(const bf16x8*)&Kt[c * HEAD + 32 + g * 8];
        bf16x8 ka10 = *(const bf16x8*)&Kt[(16 + c) * HEAD + g * 8];
        bf16x8 ka11 = *(const bf16x8*)&Kt[(16 + c) * HEAD + 32 + g * 8];

        // S^T tiles: lane holds q=c, keys g*4+r (s0) and 16+g*4+r (s1)
        f32x4 s0 = (f32x4)0.0f, s1 = (f32x4)0.0f;
        s0 = __builtin_amdgcn_mfma_f32_16x16x32_bf16(ka00, qb0, s0, 0, 0, 0);
        s0 = __builtin_amdgcn_mfma_f32_16x16x32_bf16(ka01, qb1, s0, 0, 0, 0);
        s1 = __builtin_amdgcn_mfma_f32_16x16x32_bf16(ka10, qb0, s1, 0, 0, 0);
        s1 = __builtin_amdgcn_mfma_f32_16x16x32_bf16(ka11, qb1, s1, 0, 0, 0);

        // scale + mask from preloaded bits (bit j of word = key kt*32+j)
        const unsigned int mw32 = mwords[i];
        float sv[8];
        #pragma unroll
        for (int r = 0; r < 4; ++r) {
            sv[r]     = ((mw32 >> (g * 4 + r)) & 1u)      ? -INFINITY : s0[r] * scale;
            sv[4 + r] = ((mw32 >> (16 + g * 4 + r)) & 1u) ? -INFINITY : s1[r] * scale;
        }

        // row max: in-lane tree + cross-group (lanes c, c+16, c+32, c+48)
        float mx = fmaxf(fmaxf(fmaxf(sv[0], sv[1]), fmaxf(sv[2], sv[3])),
                         fmaxf(fmaxf(sv[4], sv[5]), fmaxf(sv[6], sv[7])));
        mx = fmaxf(mx, __shfl_xor(mx, 16));
        mx = fmaxf(mx, __shfl_xor(mx, 32));

        // defer-max: rescale only when max grows past threshold (rare)
        if (!__all(mx <= m_run + 8.0f)) {
            float mn = fmaxf(m_run, mx);
            float cf = (m_run == mn) ? 1.0f : exp2f((m_run - mn) * LOG2E);
            float cfq[4];
            #pragma unroll
            for (int r = 0; r < 4; ++r)
                cfq[r] = __shfl(cf, (lane & 48) | (g * 4 + r));
            #pragma unroll
            for (int n = 0; n < 4; ++n)
                #pragma unroll
                for (int r = 0; r < 4; ++r) o[n][r] *= cfq[r];
            l_run *= cf;
            m_run = mn;
        }

        const float mb = m_run * LOG2E;
        float p[8];
        #pragma unroll
        for (int j = 0; j < 8; ++j)
            p[j] = (sv[j] <= -1e37f) ? 0.0f : exp2f(sv[j] * LOG2E - mb);
        float rs = ((p[0] + p[1]) + (p[2] + p[3])) + ((p[4] + p[5]) + (p[6] + p[7]));
        rs += __shfl_xor(rs, 16);
        rs += __shfl_xor(rs, 32);
        l_run += rs;

        // P -> wave-private LDS in A-frag layout: keys g*4+r -> kgrp g>>1
        bf16x4 p0, p1;
        #pragma unroll
        for (int r = 0; r < 4; ++r) { p0[r] = f2bf(p[r]); p1[r] = f2bf(p[4 + r]); }
        *(bf16x4*)&P_lds[w][g >> 1][c][(g & 1) * 4]       = p0;
        *(bf16x4*)&P_lds[w][2 + (g >> 1)][c][(g & 1) * 4] = p1;
        bf16x8 pa = *(bf16x8*)&P_lds[w][g][c][0];
        #pragma unroll
        for (int n = 0; n < 4; ++n)
            o[n] = __builtin_amdgcn_mfma_f32_16x16x32_bf16(pa, vb[n], o[n], 0, 0, 0);
    }

    __syncthreads();   // everyone done with P region before O overwrites it

    // publish per-wave partials (o rows: q = g*4+r; cols h = n*16+c)
    #pragma unroll
    for (int n = 0; n < 4; ++n)
        #pragma unroll
        for (int r = 0; r < 4; ++r)
            O_lds[w][g * 4 + r][n * 16 + c] = o[n][r];
    if (lane < 16) { M_lds[w][lane] = m_run; L_lds[w][lane] = l_run; }
    __syncthreads();

    // merge 8 segments: 512 threads cover 16x64 outputs, 2 cols each
    const int row  = tid >> 5;
    const int col0 = (tid & 31) * 2;
    float M = -INFINITY;
    #pragma unroll
    for (int i = 0; i < 8; ++i) M = fmaxf(M, M_lds[i][row]);
    float L = 0.0f, a0 = 0.0f, a1 = 0.0f;
    #pragma unroll
    for (int i = 0; i < 8; ++i) {
        float wgt = exp2f((M_lds[i][row] - M) * LOG2E);
        L  += L_lds[i][row] * wgt;
        a0 += O_lds[i][row][col0]     * wgt;
        a1 += O_lds[i][row][col0 + 1] * wgt;
    }
    float inv = 1.0f / L;
    float* Ob = out + (size_t)(b * SEQ + qbase + row) * HEAD;
    Ob[col0]     = a0 * inv;
    Ob[col0 + 1] = a1 * inv;
}

extern "C" void kernel_launch(void* const* d_in, const int* in_sizes, int n_in,
                              void* d_out, int out_size, void* d_ws, size_t ws_size,
                              hipStream_t stream)
{
    // setup_inputs order: key_input, query_input, value_input, mask, Wq, Wk, Wv
    const float* key_in   = (const float*)d_in[0];
    const float* query_in = (const float*)d_in[1];
    const float* value_in = (const float*)d_in[2];
    const void*  mask     = d_in[3];
    const float* Wq = (const float*)d_in[4];
    const float* Wk = (const float*)d_in[5];
    const float* Wv = (const float*)d_in[6];

    char* ws = (char*)d_ws;
    short* Qw  = (short*)ws;                            // 1 MB
    short* Kw  = Qw + (size_t)BATCH * SEQ * HEAD;       // 1 MB
    short* Vtw = Kw + (size_t)BATCH * SEQ * HEAD;       // 1 MB
    unsigned long long* packed =
        (unsigned long long*)(ws + (size_t)3 * BATCH * SEQ * HEAD * sizeof(short));  // 2 MB
    short* Wt  = (short*)((char*)packed + (size_t)NCHUNK * 8);   // 384 KB
    int* mflag = (int*)((char*)Wt + (size_t)3 * HEAD * DIM * sizeof(short));

    wconv_detect_kernel<<<dim3(16, 3), 256, 0, stream>>>(
        Wq, Wk, Wv, Wt, (const unsigned int*)mask, mflag);

    proj7_kernel<<<1536, 256, 0, stream>>>(
        query_in, key_in, value_in, Wt, Qw, Kw, Vtw);

    pack_kernel<<<512, 256, 0, stream>>>(mask, mflag, packed);

    attn_kernel<<<dim3(SEQ / 16, BATCH), 512, 0, stream>>>(
        Qw, Kw, Vtw, (const unsigned int*)packed, (float*)d_out);
}

// Round 11
// 80.773 us; speedup vs baseline: 1.0154x; 1.0154x over previous
//
#include <hip/hip_runtime.h>
#include <hip/hip_bf16.h>
#include <math.h>

#define BATCH 4
#define SEQ   2048
#define DIM   1024
#define HEAD  64
#define NCHUNK ((BATCH * SEQ * SEQ) / 64)   // 262144 64-bool chunks

typedef __attribute__((ext_vector_type(8))) short bf16x8;
typedef __attribute__((ext_vector_type(4))) short bf16x4;
typedef __attribute__((ext_vector_type(4))) float f32x4;

static __device__ __forceinline__ short f2bf(float f) {
    __hip_bfloat16 h = __float2bfloat16(f);     // RNE
    return *reinterpret_cast<short*>(&h);
}

// async global->LDS, 16B per lane; LDS dest = wave-uniform base + lane*16,
// global source address is per-lane.
static __device__ __forceinline__ void gload_lds16(const void* g, void* l) {
    __builtin_amdgcn_global_load_lds(
        (const __attribute__((address_space(1))) unsigned int*)g,
        (__attribute__((address_space(3))) unsigned int*)l, 16, 0, 0);
}

// ---------------------------------------------------------------------------
// Prelude: W[1024][64] f32 -> Wt2[which][kc16][ks2][f4][lane64][8] bf16:
// per K-chunk-64 one contiguous 8KB block whose 1KB sub-blocks are exactly
// the B-fragments in lane order (f = h>>4, lane = kgrp*16 + (h&15)).
// Plus mask dtype detect (int32 bools are {0,1}; byte-bools read as u32
// exceed 1 w.p. 7/8 per word).
// ---------------------------------------------------------------------------
__global__ __launch_bounds__(256) void wconv_detect_kernel(
    const float* __restrict__ Wq, const float* __restrict__ Wk, const float* __restrict__ Wv,
    short* __restrict__ Wt, const unsigned int* __restrict__ mask_u32,
    int* __restrict__ mflag)
{
    const int which = blockIdx.y;
    const float* __restrict__ W = (which == 0) ? Wq : (which == 1) ? Wk : Wv;

    const int h  = threadIdx.x & 63;
    const int k0 = blockIdx.x * 64 + (threadIdx.x >> 6) * 16;
    const int f  = h >> 4, c = h & 15;
    #pragma unroll
    for (int j = 0; j < 16; ++j) {
        int k  = k0 + j;
        int kc = k >> 6, ks = (k >> 5) & 1, kg = (k >> 3) & 3, kj = k & 7;
        size_t idx = ((((size_t)which * 16 + kc) * 2 + ks) * 4 + f) * 512
                     + (kg * 16 + c) * 8 + kj;
        Wt[idx] = f2bf(W[(size_t)k * HEAD + h]);
    }

    if (blockIdx.x == 0 && blockIdx.y == 0 && threadIdx.x < 64) {
        int lane = threadIdx.x;
        bool weird = false;
        for (int i = lane; i < 1024; i += 64) weird |= (mask_u32[i] > 1u);
        unsigned long long b = __ballot(weird);
        if (lane == 0) *mflag = (b != 0ull) ? 1 : 0;
    }
}

// ---------------------------------------------------------------------------
// Projection v8: X[8192,1024]f32 @ W -> bf16 Q/K/Vt.
// 1536 blocks x 256 threads (4 waves); 16 rows x 64 cols per block; each wave
// owns a 16x16 output column-group over the FULL K (no split-K, no merge).
// Counted-vmcnt triple-buffered pipeline (T4): per chunk t,
//   s_waitcnt vmcnt(3)   <- stage(t) landed, stage(t+1) stays in flight
//   s_barrier            <- raw; __syncthreads would drain vmcnt to 0 (m97 stall)
//   stage(t+2)           <- overwrites buf[(t-1)%3], safe: all waves past
//                           barrier(t) finished compute(t-1)
//   compute(t)
// X staged with XOR-swizzled SOURCE (both-sides rule), W staged lane-linear
// from the frag-major Wt2 (conflict-free b128 reads).
// Registers never hold in-flight loads -> immune to the R7-R10 scheduler
// serialization; concurrency lives in the HW vmem queue.
// ---------------------------------------------------------------------------
__global__ __launch_bounds__(256) void proj8_kernel(
    const float* __restrict__ Xq, const float* __restrict__ Xk, const float* __restrict__ Xv,
    const short* __restrict__ Wt,
    short* __restrict__ Q, short* __restrict__ K, short* __restrict__ Vt)
{
    const int which = blockIdx.x >> 9;          // 0:Q 1:K 2:V
    const int row0  = (blockIdx.x & 511) * 16;  // global row (b*S+s)
    const float* __restrict__ X = (which == 0) ? Xq : (which == 1) ? Xk : Xv;
    const char* Wg = (const char*)Wt + (size_t)which * 131072;   // 128 KB

    const int tid  = threadIdx.x;
    const int lane = tid & 63;
    const int w    = tid >> 6;                  // wave -> output cols w*16..+16
    const int g    = lane >> 4;
    const int c    = lane & 15;

    __shared__ __align__(16) char smem[3][12288];   // [buf][X 4KB | W 8KB]

    const char* Xg = (const char*)X + (size_t)row0 * 4096;

    // X staging assignment: wave w stages rows w*4..w*4+3 (1 instr, 1KB);
    // source pre-swizzled within each row's 256B chunk.
    const int srow  = w * 4 + (lane >> 4);
    const int sxoff = ((lane & 15) * 16) ^ ((srow & 7) << 4);
    const char* xsrc_base = Xg + (size_t)srow * 4096 + sxoff;

    auto stage = [&](int t) {
        char* buf = smem[t % 3];
        gload_lds16(xsrc_base + t * 256, buf + w * 1024);
        gload_lds16(Wg + (size_t)t * 8192 + (w * 2 + 0) * 1024 + lane * 16,
                    buf + 4096 + (w * 2 + 0) * 1024);
        gload_lds16(Wg + (size_t)t * 8192 + (w * 2 + 1) * 1024 + lane * 16,
                    buf + 4096 + (w * 2 + 1) * 1024);
    };

    f32x4 acc = (f32x4)0.0f;
    const int aswz = (c & 7) << 4;

    stage(0);
    stage(1);

    for (int t = 0; t < 16; ++t) {
        if (t < 15) asm volatile("s_waitcnt vmcnt(3)" ::: "memory");
        else        asm volatile("s_waitcnt vmcnt(0)" ::: "memory");
        __builtin_amdgcn_sched_barrier(0);
        __builtin_amdgcn_s_barrier();
        asm volatile("" ::: "memory");
        __builtin_amdgcn_sched_barrier(0);
        if (t < 14) stage(t + 2);

        const char* Xb = smem[t % 3] + c * 256;
        const char* Wb = smem[t % 3] + 4096;
        #pragma unroll
        for (int ks = 0; ks < 2; ++ks) {
            const int o = ks * 128 + g * 32;
            f32x4 x0 = *(const f32x4*)(Xb + ((o)      ^ aswz));
            f32x4 x1 = *(const f32x4*)(Xb + ((o + 16) ^ aswz));
            bf16x8 a;
            a[0]=f2bf(x0[0]); a[1]=f2bf(x0[1]); a[2]=f2bf(x0[2]); a[3]=f2bf(x0[3]);
            a[4]=f2bf(x1[0]); a[5]=f2bf(x1[1]); a[6]=f2bf(x1[2]); a[7]=f2bf(x1[3]);
            bf16x8 bv = *(const bf16x8*)(Wb + (ks * 4 + w) * 1024 + lane * 16);
            acc = __builtin_amdgcn_mfma_f32_16x16x32_bf16(a, bv, acc, 0, 0, 0);
        }
    }

    // epilogue: D col = c -> h = w*16+c; D row = g*4+r -> X row
    if (which < 2) {
        short* dst = (which == 0) ? Q : K;
        #pragma unroll
        for (int r = 0; r < 4; ++r)
            dst[(size_t)(row0 + g * 4 + r) * HEAD + w * 16 + c] = f2bf(acc[r]);
    } else {
        const int b  = row0 >> 11;
        const int s0 = (row0 & (SEQ - 1)) + g * 4;
        bf16x4 pk;
        #pragma unroll
        for (int r = 0; r < 4; ++r) pk[r] = f2bf(acc[r]);
        *(bf16x4*)&Vt[((size_t)(b * HEAD + w * 16 + c)) * SEQ + s0] = pk;
    }
}

// ---------------------------------------------------------------------------
// Mask bit-pack: 16 independent 256B loads in flight per wave,
// 512 blocks x 4 waves; wave owns 128 consecutive chunks. (6.1 TB/s, at floor)
// ---------------------------------------------------------------------------
__global__ __launch_bounds__(256) void pack_kernel(
    const void* __restrict__ mask, const int* __restrict__ mflag,
    unsigned long long* __restrict__ packed)
{
    const int lane = threadIdx.x & 63;
    const int gw   = blockIdx.x * 4 + (threadIdx.x >> 6);   // 0..2047
    const int c0   = gw * 128;
    const int useByte = *mflag;
    if (useByte) {
        const unsigned char* mb = (const unsigned char*)mask;
        for (int i = 0; i < 8; ++i) {
            unsigned char v[16];
            #pragma unroll
            for (int j = 0; j < 16; ++j)
                v[j] = mb[(size_t)(c0 + i * 16 + j) * 64 + lane];
            #pragma unroll
            for (int j = 0; j < 16; ++j) {
                unsigned long long bb = __ballot(v[j] != 0);
                if (lane == 0) packed[c0 + i * 16 + j] = bb;
            }
        }
    } else {
        const unsigned int* mw = (const unsigned int*)mask;
        for (int i = 0; i < 8; ++i) {
            unsigned int v[16];
            #pragma unroll
            for (int j = 0; j < 16; ++j)
                v[j] = mw[(size_t)(c0 + i * 16 + j) * 64 + lane];
            #pragma unroll
            for (int j = 0; j < 16; ++j) {
                unsigned long long bb = __ballot(v[j] != 0);
                if (lane == 0) packed[c0 + i * 16 + j] = bb;
            }
        }
    }
}

// ---------------------------------------------------------------------------
// Flash attention: grid (S/16, B), 512 threads = 8 waves; wave w owns keys
// [w*256,(w+1)*256). Swapped QK^T (S^T = mfma(K,Q)) puts a full q-row in-lane:
// softmax reduce = in-lane tree + 2 shfl_xor. Mask preloaded as 8 bit-words
// per lane. Defer-max rescale (THR=8). P->LDS transpose -> PV MFMA.
// ---------------------------------------------------------------------------
__global__ __launch_bounds__(512, 4) void attn_kernel(
    const short* __restrict__ Q, const short* __restrict__ K, const short* __restrict__ Vt,
    const unsigned int* __restrict__ packed, float* __restrict__ out)
{
    const int qbase = blockIdx.x * 16;
    const int b     = blockIdx.y;
    const int tid  = threadIdx.x;
    const int lane = tid & 63;
    const int w    = tid >> 6;          // wave 0..7 = key segment
    const int g    = lane >> 4;
    const int c    = lane & 15;

    const short* Qb = Q  + (size_t)(b * SEQ + qbase) * HEAD;
    const short* Kb = K  + (size_t)b * SEQ * HEAD;
    const short* Vb = Vt + (size_t)b * HEAD * SEQ;

    // LDS: P (loop phase, 8KB) aliases O (merge phase, 32KB); M/L after.
    __shared__ __align__(16) unsigned char smem[32768 + 1024];
    short (*P_lds)[4][16][8] = (short (*)[4][16][8])smem;   // [wave][kgrp][q][8]
    float (*O_lds)[16][64]   = (float (*)[16][64])smem;     // [wave][q][h]
    float (*M_lds)[16] = (float (*)[16])(smem + 32768);     // [wave][q]
    float (*L_lds)[16] = (float (*)[16])(smem + 32768 + 512);

    // per-lane mask bits for q = qbase+c, keys w*256..w*256+255 (8 u32 words)
    const unsigned int* pw = packed + (size_t)(b * SEQ + qbase + c) * 64 + w * 8;
    unsigned int mwords[8];
    #pragma unroll
    for (int i = 0; i < 8; ++i) mwords[i] = pw[i];

    // Q as B-operand fragments (col q = c, k = head dim)
    bf16x8 qb0 = *(const bf16x8*)&Qb[c * HEAD + g * 8];
    bf16x8 qb1 = *(const bf16x8*)&Qb[c * HEAD + 32 + g * 8];

    float m_run = -INFINITY, l_run = 0.0f;
    f32x4 o[4];
    #pragma unroll
    for (int n = 0; n < 4; ++n) o[n] = (f32x4)0.0f;

    const float scale = 0.125f;                    // HEAD^-0.5
    const float LOG2E = 1.44269504088896340736f;

    for (int i = 0; i < 8; ++i) {
        const int kt = w * 8 + i;                  // key tile of 32
        const short* Kt = Kb + (size_t)kt * 32 * HEAD;

        // V^T B-fragments (issued early, independent of QK chain)
        bf16x8 vb[4];
        #pragma unroll
        for (int n = 0; n < 4; ++n)
            vb[n] = *(const bf16x8*)&Vb[(size_t)(n * 16 + c) * SEQ + kt * 32 + g * 8];

        // K as A-operand (row = key = c / 16+c, k = head dim)
        bf16x8 ka00 = *(const bf16x8*)&Kt[c * HEAD + g * 8];
        bf16x8 ka01 = *(const bf16x8*)&Kt[c * HEAD + 32 + g * 8];
        bf16x8 ka10 = *(const bf16x8*)&Kt[(16 + c) * HEAD + g * 8];
        bf16x8 ka11 = *(const bf16x8*)&Kt[(16 + c) * HEAD + 32 + g * 8];

        // S^T tiles: lane holds q=c, keys g*4+r (s0) and 16+g*4+r (s1)
        f32x4 s0 = (f32x4)0.0f, s1 = (f32x4)0.0f;
        s0 = __builtin_amdgcn_mfma_f32_16x16x32_bf16(ka00, qb0, s0, 0, 0, 0);
        s0 = __builtin_amdgcn_mfma_f32_16x16x32_bf16(ka01, qb1, s0, 0, 0, 0);
        s1 = __builtin_amdgcn_mfma_f32_16x16x32_bf16(ka10, qb0, s1, 0, 0, 0);
        s1 = __builtin_amdgcn_mfma_f32_16x16x32_bf16(ka11, qb1, s1, 0, 0, 0);

        // scale + mask from preloaded bits (bit j of word = key kt*32+j)
        const unsigned int mw32 = mwords[i];
        float sv[8];
        #pragma unroll
        for (int r = 0; r < 4; ++r) {
            sv[r]     = ((mw32 >> (g * 4 + r)) & 1u)      ? -INFINITY : s0[r] * scale;
            sv[4 + r] = ((mw32 >> (16 + g * 4 + r)) & 1u) ? -INFINITY : s1[r] * scale;
        }

        // row max: in-lane tree + cross-group (lanes c, c+16, c+32, c+48)
        float mx = fmaxf(fmaxf(fmaxf(sv[0], sv[1]), fmaxf(sv[2], sv[3])),
                         fmaxf(fmaxf(sv[4], sv[5]), fmaxf(sv[6], sv[7])));
        mx = fmaxf(mx, __shfl_xor(mx, 16));
        mx = fmaxf(mx, __shfl_xor(mx, 32));

        // defer-max: rescale only when max grows past threshold (rare)
        if (!__all(mx <= m_run + 8.0f)) {
            float mn = fmaxf(m_run, mx);
            float cf = (m_run == mn) ? 1.0f : exp2f((m_run - mn) * LOG2E);
            float cfq[4];
            #pragma unroll
            for (int r = 0; r < 4; ++r)
                cfq[r] = __shfl(cf, (lane & 48) | (g * 4 + r));
            #pragma unroll
            for (int n = 0; n < 4; ++n)
                #pragma unroll
                for (int r = 0; r < 4; ++r) o[n][r] *= cfq[r];
            l_run *= cf;
            m_run = mn;
        }

        const float mb = m_run * LOG2E;
        float p[8];
        #pragma unroll
        for (int j = 0; j < 8; ++j)
            p[j] = (sv[j] <= -1e37f) ? 0.0f : exp2f(sv[j] * LOG2E - mb);
        float rs = ((p[0] + p[1]) + (p[2] + p[3])) + ((p[4] + p[5]) + (p[6] + p[7]));
        rs += __shfl_xor(rs, 16);
        rs += __shfl_xor(rs, 32);
        l_run += rs;

        // P -> wave-private LDS in A-frag layout: keys g*4+r -> kgrp g>>1
        bf16x4 p0, p1;
        #pragma unroll
        for (int r = 0; r < 4; ++r) { p0[r] = f2bf(p[r]); p1[r] = f2bf(p[4 + r]); }
        *(bf16x4*)&P_lds[w][g >> 1][c][(g & 1) * 4]       = p0;
        *(bf16x4*)&P_lds[w][2 + (g >> 1)][c][(g & 1) * 4] = p1;
        bf16x8 pa = *(bf16x8*)&P_lds[w][g][c][0];
        #pragma unroll
        for (int n = 0; n < 4; ++n)
            o[n] = __builtin_amdgcn_mfma_f32_16x16x32_bf16(pa, vb[n], o[n], 0, 0, 0);
    }

    __syncthreads();   // everyone done with P region before O overwrites it

    // publish per-wave partials (o rows: q = g*4+r; cols h = n*16+c)
    #pragma unroll
    for (int n = 0; n < 4; ++n)
        #pragma unroll
        for (int r = 0; r < 4; ++r)
            O_lds[w][g * 4 + r][n * 16 + c] = o[n][r];
    if (lane < 16) { M_lds[w][lane] = m_run; L_lds[w][lane] = l_run; }
    __syncthreads();

    // merge 8 segments: 512 threads cover 16x64 outputs, 2 cols each
    const int row  = tid >> 5;
    const int col0 = (tid & 31) * 2;
    float M = -INFINITY;
    #pragma unroll
    for (int i = 0; i < 8; ++i) M = fmaxf(M, M_lds[i][row]);
    float L = 0.0f, a0 = 0.0f, a1 = 0.0f;
    #pragma unroll
    for (int i = 0; i < 8; ++i) {
        float wgt = exp2f((M_lds[i][row] - M) * LOG2E);
        L  += L_lds[i][row] * wgt;
        a0 += O_lds[i][row][col0]     * wgt;
        a1 += O_lds[i][row][col0 + 1] * wgt;
    }
    float inv = 1.0f / L;
    float* Ob = out + (size_t)(b * SEQ + qbase + row) * HEAD;
    Ob[col0]     = a0 * inv;
    Ob[col0 + 1] = a1 * inv;
}

extern "C" void kernel_launch(void* const* d_in, const int* in_sizes, int n_in,
                              void* d_out, int out_size, void* d_ws, size_t ws_size,
                              hipStream_t stream)
{
    // setup_inputs order: key_input, query_input, value_input, mask, Wq, Wk, Wv
    const float* key_in   = (const float*)d_in[0];
    const float* query_in = (const float*)d_in[1];
    const float* value_in = (const float*)d_in[2];
    const void*  mask     = d_in[3];
    const float* Wq = (const float*)d_in[4];
    const float* Wk = (const float*)d_in[5];
    const float* Wv = (const float*)d_in[6];

    char* ws = (char*)d_ws;
    short* Qw  = (short*)ws;                            // 1 MB
    short* Kw  = Qw + (size_t)BATCH * SEQ * HEAD;       // 1 MB
    short* Vtw = Kw + (size_t)BATCH * SEQ * HEAD;       // 1 MB
    unsigned long long* packed =
        (unsigned long long*)(ws + (size_t)3 * BATCH * SEQ * HEAD * sizeof(short));  // 2 MB
    short* Wt  = (short*)((char*)packed + (size_t)NCHUNK * 8);   // 384 KB
    int* mflag = (int*)((char*)Wt + (size_t)3 * HEAD * DIM * sizeof(short));

    wconv_detect_kernel<<<dim3(16, 3), 256, 0, stream>>>(
        Wq, Wk, Wv, Wt, (const unsigned int*)mask, mflag);

    proj8_kernel<<<1536, 256, 0, stream>>>(
        query_in, key_in, value_in, Wt, Qw, Kw, Vtw);

    pack_kernel<<<512, 256, 0, stream>>>(mask, mflag, packed);

    attn_kernel<<<dim3(SEQ / 16, BATCH), 512, 0, stream>>>(
        Qw, Kw, Vtw, (const unsigned int*)packed, (float*)d_out);
}

// Round 12
// 73.861 us; speedup vs baseline: 1.1104x; 1.0936x over previous
//
#include <hip/hip_runtime.h>
#include <hip/hip_bf16.h>
#include <math.h>

#define BATCH 4
#define SEQ   2048
#define DIM   1024
#define HEAD  64
#define NCHUNK ((BATCH * SEQ * SEQ) / 64)   // 262144 64-bool chunks

typedef __attribute__((ext_vector_type(8))) short bf16x8;
typedef __attribute__((ext_vector_type(4))) short bf16x4;
typedef __attribute__((ext_vector_type(4))) float f32x4;

static __device__ __forceinline__ short f2bf(float f) {
    __hip_bfloat16 h = __float2bfloat16(f);     // RNE
    return *reinterpret_cast<short*>(&h);
}

// ---------------------------------------------------------------------------
// Prelude: W[1024][64] f32 -> frag-major Wt2[which][k/32][64][32] bf16, so a
// proj wave's B-frag load (n,c,g lanes) is one contiguous 1KB segment.
// Plus mask dtype detect (int32 bools are {0,1}; byte-bools read as u32
// exceed 1 w.p. 7/8 per word).
// ---------------------------------------------------------------------------
__global__ __launch_bounds__(256) void wconv_detect_kernel(
    const float* __restrict__ Wq, const float* __restrict__ Wk, const float* __restrict__ Wv,
    short* __restrict__ Wt, const unsigned int* __restrict__ mask_u32,
    int* __restrict__ mflag)
{
    const int which = blockIdx.y;
    const float* __restrict__ W = (which == 0) ? Wq : (which == 1) ? Wk : Wv;
    short* __restrict__ Wtw = Wt + (size_t)which * HEAD * DIM;

    const int h  = threadIdx.x & 63;
    const int k0 = blockIdx.x * 64 + (threadIdx.x >> 6) * 16;
    #pragma unroll
    for (int j = 0; j < 16; ++j) {
        int k = k0 + j;
        Wtw[((size_t)(k >> 5) * 64 + h) * 32 + (k & 31)] =
            f2bf(W[(size_t)k * HEAD + h]);
    }

    if (blockIdx.x == 0 && blockIdx.y == 0 && threadIdx.x < 64) {
        int lane = threadIdx.x;
        bool weird = false;
        for (int i = lane; i < 1024; i += 64) weird |= (mask_u32[i] > 1u);
        unsigned long long b = __ballot(weird);
        if (lane == 0) *mflag = (b != 0ull) ? 1 : 0;
    }
}

// ---------------------------------------------------------------------------
// Fused prep: grid 2048 x 256.
//   blocks [0,512):    mask bit-pack (67 MB stream; rides the memory-idle
//                      issue slots of the co-resident proj blocks)
//   blocks [512,2048): projection X[8192,1024]f32 @ W -> bf16 Q/K/Vt
//                      (proj5 core: best-measured 41.5 us; 16 rows x 64 cols,
//                      4 waves split-K 256, 16 KB LDS merge, frag-major W)
// Rationale: 7 proj structures all land 41-53 us with CUs ~90% idle on
// memory waits (replay at L3-warm = same duration). pack previously ran
// sequentially after proj; fusing overlaps its 67 MB stream with proj's
// stalls. Expected fused ~= max(proj, pack), saving ~10 us of wall time.
// ---------------------------------------------------------------------------
__global__ __launch_bounds__(256, 4) void prep_kernel(
    const float* __restrict__ Xq, const float* __restrict__ Xk, const float* __restrict__ Xv,
    const short* __restrict__ Wt, const void* __restrict__ mask,
    const int* __restrict__ mflag, unsigned long long* __restrict__ packed,
    short* __restrict__ Q, short* __restrict__ K, short* __restrict__ Vt)
{
    const int bx  = blockIdx.x;
    const int tid = threadIdx.x;
    const int lane = tid & 63;
    const int w    = tid >> 6;

    if (bx < 512) {
        // ------------------------- mask pack -------------------------
        const int gw = bx * 4 + w;                // 0..2047
        const int c0 = gw * 128;
        const int useByte = *mflag;
        if (useByte) {
            const unsigned char* mb = (const unsigned char*)mask;
            for (int i = 0; i < 8; ++i) {
                unsigned char v[16];
                #pragma unroll
                for (int j = 0; j < 16; ++j)
                    v[j] = mb[(size_t)(c0 + i * 16 + j) * 64 + lane];
                #pragma unroll
                for (int j = 0; j < 16; ++j) {
                    unsigned long long bb = __ballot(v[j] != 0);
                    if (lane == 0) packed[c0 + i * 16 + j] = bb;
                }
            }
        } else {
            const unsigned int* mw = (const unsigned int*)mask;
            for (int i = 0; i < 8; ++i) {
                unsigned int v[16];
                #pragma unroll
                for (int j = 0; j < 16; ++j)
                    v[j] = mw[(size_t)(c0 + i * 16 + j) * 64 + lane];
                #pragma unroll
                for (int j = 0; j < 16; ++j) {
                    unsigned long long bb = __ballot(v[j] != 0);
                    if (lane == 0) packed[c0 + i * 16 + j] = bb;
                }
            }
        }
        return;
    }

    // ------------------------- projection (proj5 core) -------------------------
    __shared__ float O_lds[4][16][64];          // [wave][row][col] partials

    const int pi    = bx - 512;
    const int which = pi >> 9;                  // 0:Q 1:K 2:V
    const int row0  = (pi & 511) * 16;          // global row (b*S+s)
    const float* __restrict__ X = (which == 0) ? Xq : (which == 1) ? Xk : Xv;
    const short* __restrict__ Wtw = Wt + (size_t)which * HEAD * DIM;

    const int g = lane >> 4;
    const int c = lane & 15;

    const float* __restrict__ Xp = X + (size_t)(row0 + c) * DIM + w * 256 + g * 8;
    // frag-major W: chunk (w*8 + half*4 + s), lane offset (n*16+c)*32 + g*8
    const short* __restrict__ Wp = Wtw + (size_t)(w * 8) * 2048 + c * 32 + g * 8;

    f32x4 acc[4];
    #pragma unroll
    for (int n = 0; n < 4; ++n) acc[n] = (f32x4)0.0f;

    #pragma unroll
    for (int half = 0; half < 2; ++half) {
        f32x4 xa[4], xb[4];
        #pragma unroll
        for (int s = 0; s < 4; ++s) {
            xa[s] = *(const f32x4*)(Xp + half * 128 + s * 32);
            xb[s] = *(const f32x4*)(Xp + half * 128 + s * 32 + 4);
        }
        bf16x8 wf[16];
        #pragma unroll
        for (int s = 0; s < 4; ++s)
            #pragma unroll
            for (int n = 0; n < 4; ++n)
                wf[s * 4 + n] = *(const bf16x8*)(Wp + (size_t)(half * 4 + s) * 2048
                                                 + n * 512);
        #pragma unroll
        for (int s = 0; s < 4; ++s) {
            bf16x8 a;
            a[0]=f2bf(xa[s][0]); a[1]=f2bf(xa[s][1]); a[2]=f2bf(xa[s][2]); a[3]=f2bf(xa[s][3]);
            a[4]=f2bf(xb[s][0]); a[5]=f2bf(xb[s][1]); a[6]=f2bf(xb[s][2]); a[7]=f2bf(xb[s][3]);
            #pragma unroll
            for (int n = 0; n < 4; ++n)
                acc[n] = __builtin_amdgcn_mfma_f32_16x16x32_bf16(a, wf[s * 4 + n],
                                                                 acc[n], 0, 0, 0);
        }
    }

    // publish partials: C/D layout col = lane&15 (W col), row = g*4+reg (X row)
    #pragma unroll
    for (int n = 0; n < 4; ++n)
        #pragma unroll
        for (int r = 0; r < 4; ++r)
            O_lds[w][g * 4 + r][n * 16 + c] = acc[n][r];
    __syncthreads();

    if (which < 2) {
        short* dst = (which == 0) ? Q : K;
        const int trow = tid >> 4, c4 = (tid & 15) * 4;
        f32x4 sum = *(const f32x4*)&O_lds[0][trow][c4];
        #pragma unroll
        for (int i = 1; i < 4; ++i) {
            f32x4 t = *(const f32x4*)&O_lds[i][trow][c4];
            sum[0] += t[0]; sum[1] += t[1]; sum[2] += t[2]; sum[3] += t[3];
        }
        bf16x4 pk;
        #pragma unroll
        for (int j = 0; j < 4; ++j) pk[j] = f2bf(sum[j]);
        *(bf16x4*)&dst[(size_t)(row0 + trow) * HEAD + c4] = pk;
    } else {
        // Vt[b][h][s]: thread owns one h, 4 consecutive s
        const int h = tid & 63, r4 = (tid >> 6) * 4;
        const int b = row0 >> 11, sb = row0 & (SEQ - 1);
        bf16x4 pk;
        #pragma unroll
        for (int j = 0; j < 4; ++j) {
            float v = O_lds[0][r4 + j][h] + O_lds[1][r4 + j][h]
                    + O_lds[2][r4 + j][h] + O_lds[3][r4 + j][h];
            pk[j] = f2bf(v);
        }
        *(bf16x4*)&Vt[((size_t)(b * HEAD + h)) * SEQ + sb + r4] = pk;
    }
}

// ---------------------------------------------------------------------------
// Flash attention: grid (S/16, B), 512 threads = 8 waves; wave w owns keys
// [w*256,(w+1)*256). Swapped QK^T (S^T = mfma(K,Q)) puts a full q-row in-lane:
// softmax reduce = in-lane tree + 2 shfl_xor. Mask preloaded as 8 bit-words
// per lane. Defer-max rescale (THR=8). P->LDS transpose -> PV MFMA.
// ---------------------------------------------------------------------------
__global__ __launch_bounds__(512, 4) void attn_kernel(
    const short* __restrict__ Q, const short* __restrict__ K, const short* __restrict__ Vt,
    const unsigned int* __restrict__ packed, float* __restrict__ out)
{
    const int qbase = blockIdx.x * 16;
    const int b     = blockIdx.y;
    const int tid  = threadIdx.x;
    const int lane = tid & 63;
    const int w    = tid >> 6;          // wave 0..7 = key segment
    const int g    = lane >> 4;
    const int c    = lane & 15;

    const short* Qb = Q  + (size_t)(b * SEQ + qbase) * HEAD;
    const short* Kb = K  + (size_t)b * SEQ * HEAD;
    const short* Vb = Vt + (size_t)b * HEAD * SEQ;

    // LDS: P (loop phase, 8KB) aliases O (merge phase, 32KB); M/L after.
    __shared__ __align__(16) unsigned char smem[32768 + 1024];
    short (*P_lds)[4][16][8] = (short (*)[4][16][8])smem;   // [wave][kgrp][q][8]
    float (*O_lds)[16][64]   = (float (*)[16][64])smem;     // [wave][q][h]
    float (*M_lds)[16] = (float (*)[16])(smem + 32768);     // [wave][q]
    float (*L_lds)[16] = (float (*)[16])(smem + 32768 + 512);

    // per-lane mask bits for q = qbase+c, keys w*256..w*256+255 (8 u32 words)
    const unsigned int* pw = packed + (size_t)(b * SEQ + qbase + c) * 64 + w * 8;
    unsigned int mwords[8];
    #pragma unroll
    for (int i = 0; i < 8; ++i) mwords[i] = pw[i];

    // Q as B-operand fragments (col q = c, k = head dim)
    bf16x8 qb0 = *(const bf16x8*)&Qb[c * HEAD + g * 8];
    bf16x8 qb1 = *(const bf16x8*)&Qb[c * HEAD + 32 + g * 8];

    float m_run = -INFINITY, l_run = 0.0f;
    f32x4 o[4];
    #pragma unroll
    for (int n = 0; n < 4; ++n) o[n] = (f32x4)0.0f;

    const float scale = 0.125f;                    // HEAD^-0.5
    const float LOG2E = 1.44269504088896340736f;

    for (int i = 0; i < 8; ++i) {
        const int kt = w * 8 + i;                  // key tile of 32
        const short* Kt = Kb + (size_t)kt * 32 * HEAD;

        // V^T B-fragments (issued early, independent of QK chain)
        bf16x8 vb[4];
        #pragma unroll
        for (int n = 0; n < 4; ++n)
            vb[n] = *(const bf16x8*)&Vb[(size_t)(n * 16 + c) * SEQ + kt * 32 + g * 8];

        // K as A-operand (row = key = c / 16+c, k = head dim)
        bf16x8 ka00 = *(const bf16x8*)&Kt[c * HEAD + g * 8];
        bf16x8 ka01 = *(const bf16x8*)&Kt[c * HEAD + 32 + g * 8];
        bf16x8 ka10 = *(const bf16x8*)&Kt[(16 + c) * HEAD + g * 8];
        bf16x8 ka11 = *(const bf16x8*)&Kt[(16 + c) * HEAD + 32 + g * 8];

        // S^T tiles: lane holds q=c, keys g*4+r (s0) and 16+g*4+r (s1)
        f32x4 s0 = (f32x4)0.0f, s1 = (f32x4)0.0f;
        s0 = __builtin_amdgcn_mfma_f32_16x16x32_bf16(ka00, qb0, s0, 0, 0, 0);
        s0 = __builtin_amdgcn_mfma_f32_16x16x32_bf16(ka01, qb1, s0, 0, 0, 0);
        s1 = __builtin_amdgcn_mfma_f32_16x16x32_bf16(ka10, qb0, s1, 0, 0, 0);
        s1 = __builtin_amdgcn_mfma_f32_16x16x32_bf16(ka11, qb1, s1, 0, 0, 0);

        // scale + mask from preloaded bits (bit j of word = key kt*32+j)
        const unsigned int mw32 = mwords[i];
        float sv[8];
        #pragma unroll
        for (int r = 0; r < 4; ++r) {
            sv[r]     = ((mw32 >> (g * 4 + r)) & 1u)      ? -INFINITY : s0[r] * scale;
            sv[4 + r] = ((mw32 >> (16 + g * 4 + r)) & 1u) ? -INFINITY : s1[r] * scale;
        }

        // row max: in-lane tree + cross-group (lanes c, c+16, c+32, c+48)
        float mx = fmaxf(fmaxf(fmaxf(sv[0], sv[1]), fmaxf(sv[2], sv[3])),
                         fmaxf(fmaxf(sv[4], sv[5]), fmaxf(sv[6], sv[7])));
        mx = fmaxf(mx, __shfl_xor(mx, 16));
        mx = fmaxf(mx, __shfl_xor(mx, 32));

        // defer-max: rescale only when max grows past threshold (rare)
        if (!__all(mx <= m_run + 8.0f)) {
            float mn = fmaxf(m_run, mx);
            float cf = (m_run == mn) ? 1.0f : exp2f((m_run - mn) * LOG2E);
            float cfq[4];
            #pragma unroll
            for (int r = 0; r < 4; ++r)
                cfq[r] = __shfl(cf, (lane & 48) | (g * 4 + r));
            #pragma unroll
            for (int n = 0; n < 4; ++n)
                #pragma unroll
                for (int r = 0; r < 4; ++r) o[n][r] *= cfq[r];
            l_run *= cf;
            m_run = mn;
        }

        const float mb = m_run * LOG2E;
        float p[8];
        #pragma unroll
        for (int j = 0; j < 8; ++j)
            p[j] = (sv[j] <= -1e37f) ? 0.0f : exp2f(sv[j] * LOG2E - mb);
        float rs = ((p[0] + p[1]) + (p[2] + p[3])) + ((p[4] + p[5]) + (p[6] + p[7]));
        rs += __shfl_xor(rs, 16);
        rs += __shfl_xor(rs, 32);
        l_run += rs;

        // P -> wave-private LDS in A-frag layout: keys g*4+r -> kgrp g>>1
        bf16x4 p0, p1;
        #pragma unroll
        for (int r = 0; r < 4; ++r) { p0[r] = f2bf(p[r]); p1[r] = f2bf(p[4 + r]); }
        *(bf16x4*)&P_lds[w][g >> 1][c][(g & 1) * 4]       = p0;
        *(bf16x4*)&P_lds[w][2 + (g >> 1)][c][(g & 1) * 4] = p1;
        bf16x8 pa = *(bf16x8*)&P_lds[w][g][c][0];
        #pragma unroll
        for (int n = 0; n < 4; ++n)
            o[n] = __builtin_amdgcn_mfma_f32_16x16x32_bf16(pa, vb[n], o[n], 0, 0, 0);
    }

    __syncthreads();   // everyone done with P region before O overwrites it

    // publish per-wave partials (o rows: q = g*4+r; cols h = n*16+c)
    #pragma unroll
    for (int n = 0; n < 4; ++n)
        #pragma unroll
        for (int r = 0; r < 4; ++r)
            O_lds[w][g * 4 + r][n * 16 + c] = o[n][r];
    if (lane < 16) { M_lds[w][lane] = m_run; L_lds[w][lane] = l_run; }
    __syncthreads();

    // merge 8 segments: 512 threads cover 16x64 outputs, 2 cols each
    const int row  = tid >> 5;
    const int col0 = (tid & 31) * 2;
    float M = -INFINITY;
    #pragma unroll
    for (int i = 0; i < 8; ++i) M = fmaxf(M, M_lds[i][row]);
    float L = 0.0f, a0 = 0.0f, a1 = 0.0f;
    #pragma unroll
    for (int i = 0; i < 8; ++i) {
        float wgt = exp2f((M_lds[i][row] - M) * LOG2E);
        L  += L_lds[i][row] * wgt;
        a0 += O_lds[i][row][col0]     * wgt;
        a1 += O_lds[i][row][col0 + 1] * wgt;
    }
    float inv = 1.0f / L;
    float* Ob = out + (size_t)(b * SEQ + qbase + row) * HEAD;
    Ob[col0]     = a0 * inv;
    Ob[col0 + 1] = a1 * inv;
}

extern "C" void kernel_launch(void* const* d_in, const int* in_sizes, int n_in,
                              void* d_out, int out_size, void* d_ws, size_t ws_size,
                              hipStream_t stream)
{
    // setup_inputs order: key_input, query_input, value_input, mask, Wq, Wk, Wv
    const float* key_in   = (const float*)d_in[0];
    const float* query_in = (const float*)d_in[1];
    const float* value_in = (const float*)d_in[2];
    const void*  mask     = d_in[3];
    const float* Wq = (const float*)d_in[4];
    const float* Wk = (const float*)d_in[5];
    const float* Wv = (const float*)d_in[6];

    char* ws = (char*)d_ws;
    short* Qw  = (short*)ws;                            // 1 MB
    short* Kw  = Qw + (size_t)BATCH * SEQ * HEAD;       // 1 MB
    short* Vtw = Kw + (size_t)BATCH * SEQ * HEAD;       // 1 MB
    unsigned long long* packed =
        (unsigned long long*)(ws + (size_t)3 * BATCH * SEQ * HEAD * sizeof(short));  // 2 MB
    short* Wt  = (short*)((char*)packed + (size_t)NCHUNK * 8);   // 384 KB
    int* mflag = (int*)((char*)Wt + (size_t)3 * HEAD * DIM * sizeof(short));

    wconv_detect_kernel<<<dim3(16, 3), 256, 0, stream>>>(
        Wq, Wk, Wv, Wt, (const unsigned int*)mask, mflag);

    prep_kernel<<<2048, 256, 0, stream>>>(
        query_in, key_in, value_in, Wt, mask, mflag, packed, Qw, Kw, Vtw);

    attn_kernel<<<dim3(SEQ / 16, BATCH), 512, 0, stream>>>(
        Qw, Kw, Vtw, (const unsigned int*)packed, (float*)d_out);
}